// Round 1
// 348.084 us; speedup vs baseline: 1.0221x; 1.0221x over previous
//
#include <hip/hip_runtime.h>

typedef unsigned short u16;
typedef __attribute__((ext_vector_type(8))) short short8;
typedef __attribute__((ext_vector_type(4))) float f32x4;
typedef __attribute__((ext_vector_type(8))) unsigned short ushort8;
typedef __attribute__((ext_vector_type(4))) unsigned short ushort4v;

__device__ __forceinline__ u16 f2bf(float f) {
    unsigned int u = __float_as_uint(f);
    u += 0x7FFFu + ((u >> 16) & 1u);   // round-to-nearest-even
    return (u16)(u >> 16);
}
__device__ __forceinline__ float bf2f(u16 h) {
    return __uint_as_float(((unsigned int)h) << 16);
}

__device__ __forceinline__ void gld_lds16(const void* g, void* l) {
    __builtin_amdgcn_global_load_lds(
        (const __attribute__((address_space(1))) unsigned int*)g,
        (__attribute__((address_space(3))) unsigned int*)l,
        16, 0, 0);
}

#define WAITV(N) asm volatile("s_waitcnt vmcnt(" #N ")" ::: "memory")
#define BAR()    __builtin_amdgcn_s_barrier()

// ---------------------------------------------------------------------------
// 8-phase 256x256 bf16 GEMM (HK-style schedule in plain HIP).
// C = alpha * A[M,K] * B[N,K]^T.  512 threads = 8 waves (2 M x 4 N),
// BK=64, double-buffered 128 KiB LDS, counted vmcnt (never 0 in steady
// state), raw s_barrier (no full drain), setprio(1) around MFMA clusters.
//
// LDS swizzle: 16B granule gs = g ^ (row & 7) -> conflict-free ds_read_b128
// (2-way residual = free).  Write side realized by permuting the per-lane
// GLOBAL source granule (stays inside each row's 128B line, coalescing
// kept); LDS destination is lane-linear as global_load_lds requires.
//
// Staging schedule per K-tile kt (buffer p = kt&1):
//   ph1: rd A(half0)+B(n0,1) | stage (kt+1).A0 -> buf p^1 | BAR | MFMA q(0,0) | BAR
//   ph2: rd B(n2,3)          | stage (kt+1).A1            | BAR | MFMA q(0,1) | BAR
//   ph3: rd A(half1)         | stage (kt+2).B0 -> buf p   | BAR | MFMA q(1,1) | BAR
//   ph4:                     | stage (kt+2).B1, vmcnt(4)  | BAR | MFMA q(1,0) | BAR
// WAR safety: kt's B reads finish by ph2-end barrier (B0/B1 overwritten at
// ph3/ph4); buf p^1's A reads finished at (kt-1).ph3-end barrier.
// RAW: vmcnt(4) at ph4 completes all of tile kt+1, leaves (kt+2).B in flight.
//
// MODE 0: fused QKV.  A=xbf[16384,768], B=wt[2304,768]. grid 576.
// MODE 1: logits S_b = 0.125 * Q_b K_b^T. grid 512 (batch = xcd).
// MODE 2: out_b = A_b V_b (fp32 out). grid 192 (batch = xcd).
// ---------------------------------------------------------------------------
template <int MODE>
__global__ __launch_bounds__(512, 2) void gemm256(
    const u16* __restrict__ A, const u16* __restrict__ B,
    void* __restrict__ O0, void* __restrict__ O1, void* __restrict__ O2,
    float alpha)
{
    constexpr int K   = (MODE == 2) ? 2048 : 768;
    constexpr int NKT = K / 64;
    constexpr int lda = (MODE == 2) ? 2048 : 768;
    constexpr int ldb = (MODE == 2) ? 2048 : 768;

    __shared__ u16 lds[65536];  // A: [2 buf][256][64] @0, B: same @32768 (u16 units)

    const int f = blockIdx.x;
    const int xcd = f & 7;
    const int u = f >> 3;

    int tm, bn, cn, which = 0;
    long aoff = 0, boff = 0;
    if constexpr (MODE == 0) {
        const int c = u >> 3, rl = u & 7;      // c: 0..8 col-tile, rl: row-tile in XCD chunk
        tm = (xcd * 8 + rl) * 256;
        bn = c * 256;
        which = c / 3;
        cn = (c % 3) * 256;
    } else if constexpr (MODE == 1) {
        const int c = u >> 3, rl = u & 7;
        tm = rl * 256;
        bn = cn = c * 256;
        aoff = (long)xcd * 2048 * 768;
        boff = aoff;
    } else {
        const int c = u >> 3, rl = u & 7;      // c: 0..2, rl: 0..7
        tm = rl * 256;
        bn = cn = c * 256;
        aoff = (long)xcd * 2048 * 2048;
        boff = (long)xcd * 768 * 2048;
    }

    const int tid  = threadIdx.x;
    const int lane = tid & 63;
    const int wave = tid >> 6;
    const int wr = wave >> 2;      // 0..1  -> rows wr*128..+127
    const int wc = wave & 3;       // 0..3  -> cols wc*64..+63

    // --- staging: thread -> (row, swizzled global granule) ---
    const int srow = tid >> 3;                        // 0..63 (row in 64-row chunk)
    const int gcol = ((tid & 7) ^ (srow & 7)) << 3;   // pre-swizzled k-granule (elems)
    const int sdst = tid * 8;                         // u16 offset of this 16B slot
    const u16* Ag = A + aoff + (long)(tm + srow) * lda + gcol;
    const u16* Bg = B + boff + (long)(bn + srow) * ldb + gcol;

#define STAGE_A(KT, BO, H) do { \
    const u16* _g = Ag + (long)(KT) * 64 + (long)(H) * 128 * lda; \
    gld_lds16(_g,                  lds + (BO) + (H) * 8192 + sdst); \
    gld_lds16(_g + 64 * (long)lda, lds + (BO) + (H) * 8192 + 4096 + sdst); \
} while (0)
#define STAGE_B(KT, BO, H) do { \
    const u16* _g = Bg + (long)(KT) * 64 + (long)(H) * 128 * ldb; \
    gld_lds16(_g,                  lds + 32768 + (BO) + (H) * 8192 + sdst); \
    gld_lds16(_g + 64 * (long)ldb, lds + 32768 + (BO) + (H) * 8192 + 4096 + sdst); \
} while (0)

    // --- fragment read bases.  row&7 == lane&7 for all fragment rows. ---
    const int rrow = lane & 15;
    const int g0 = (lane >> 4) ^ (lane & 7);          // ks=0 granule; ks=1: g0^4
    const u16* a_rd0 = lds + (wr * 128 + rrow) * 64 + g0 * 8;
    const u16* a_rd1 = lds + (wr * 128 + rrow) * 64 + (g0 ^ 4) * 8;
    const u16* b_rd0 = lds + 32768 + (wc * 64 + rrow) * 64 + g0 * 8;
    const u16* b_rd1 = lds + 32768 + (wc * 64 + rrow) * 64 + (g0 ^ 4) * 8;

    short8 a[4][2], b[4][2];
    f32x4 acc[8][4] = {};

#define RD_A(BO, MH) do { _Pragma("unroll") \
    for (int m = 0; m < 4; ++m) { \
        a[m][0] = *(const short8*)(a_rd0 + (BO) + (MH) * 4096 + m * 1024); \
        a[m][1] = *(const short8*)(a_rd1 + (BO) + (MH) * 4096 + m * 1024); } \
} while (0)
#define RD_B(BO, NH) do { _Pragma("unroll") \
    for (int n = 0; n < 2; ++n) { \
        b[(NH) * 2 + n][0] = *(const short8*)(b_rd0 + (BO) + ((NH) * 2 + n) * 1024); \
        b[(NH) * 2 + n][1] = *(const short8*)(b_rd1 + (BO) + ((NH) * 2 + n) * 1024); } \
} while (0)
#define QUAD(MH, NH) do { \
    __builtin_amdgcn_s_setprio(1); \
    _Pragma("unroll") for (int ks = 0; ks < 2; ++ks) \
    _Pragma("unroll") for (int m = 0; m < 4; ++m) \
    _Pragma("unroll") for (int n = 0; n < 2; ++n) \
        acc[(MH) * 4 + m][(NH) * 2 + n] = __builtin_amdgcn_mfma_f32_16x16x32_bf16( \
            a[m][ks], b[(NH) * 2 + n][ks], acc[(MH) * 4 + m][(NH) * 2 + n], 0, 0, 0); \
    __builtin_amdgcn_s_setprio(0); \
} while (0)

#define KTILE(KT, BO, BO_N) do { \
    RD_A(BO, 0); RD_B(BO, 0); \
    if ((KT) + 1 < NKT) STAGE_A((KT) + 1, BO_N, 0); \
    BAR(); QUAD(0, 0); BAR(); \
    RD_B(BO, 1); \
    if ((KT) + 1 < NKT) STAGE_A((KT) + 1, BO_N, 1); \
    BAR(); QUAD(0, 1); BAR(); \
    RD_A(BO, 1); \
    if ((KT) + 2 < NKT) STAGE_B((KT) + 2, BO, 0); \
    BAR(); QUAD(1, 1); BAR(); \
    if ((KT) + 2 < NKT) { STAGE_B((KT) + 2, BO, 1); WAITV(4); } else { WAITV(0); } \
    BAR(); QUAD(1, 0); BAR(); \
} while (0)

    // prologue: tile0 fully + tile1's B halves; complete tile0, keep 4 in flight
    STAGE_A(0, 0, 0); STAGE_A(0, 0, 1);
    STAGE_B(0, 0, 0); STAGE_B(0, 0, 1);
    STAGE_B(1, 16384, 0); STAGE_B(1, 16384, 1);
    WAITV(4);
    BAR();

#pragma unroll 1
    for (int kt = 0; kt < NKT; kt += 2) {
        KTILE(kt, 0, 16384);
        KTILE(kt + 1, 16384, 0);
    }

    // epilogue: C/D layout col = lane&15, row = (lane>>4)*4 + r
#pragma unroll
    for (int i = 0; i < 8; ++i) {
        const int row0 = tm + wr * 128 + i * 16 + ((lane >> 4) << 2);
#pragma unroll
        for (int j = 0; j < 4; ++j) {
            const int col = cn + wc * 64 + j * 16 + (lane & 15);
#pragma unroll
            for (int r = 0; r < 4; ++r) {
                const int row = row0 + r;
                const float val = acc[i][j][r] * alpha;
                if constexpr (MODE == 0) {
                    if (which == 0)
                        ((u16*)O0)[(long)row * 768 + col] = f2bf(val);
                    else if (which == 1)
                        ((u16*)O1)[(long)row * 768 + col] = f2bf(val);
                    else  // V^T: [b, col, s]
                        ((u16*)O2)[((long)(row >> 11) * 768 + col) * 2048 + (row & 2047)] = f2bf(val);
                } else if constexpr (MODE == 1) {
                    ((u16*)O0)[(long)xcd * 2048 * 2048 + (long)row * 2048 + col] = f2bf(val);
                } else {
                    ((float*)O0)[(long)xcd * 2048 * 768 + (long)row * 768 + col] = val;
                }
            }
        }
    }
#undef KTILE
#undef QUAD
#undef RD_A
#undef RD_B
#undef STAGE_A
#undef STAGE_B
}

// ---------------------------------------------------------------------------
__global__ __launch_bounds__(256) void cvt_x_kernel(
    const float4* __restrict__ x, ushort4v* __restrict__ out, int n4)
{
    int i = blockIdx.x * 256 + threadIdx.x;
    if (i < n4) {
        float4 f = x[i];
        ushort4v o;
        o.x = f2bf(f.x); o.y = f2bf(f.y); o.z = f2bf(f.z); o.w = f2bf(f.w);
        out[i] = o;
    }
}

// w[3][768][768] (m,d,o)  ->  wt[3][768][768] (m,o,d), bf16
__global__ __launch_bounds__(256) void cvt_w_kernel(
    const float* __restrict__ w, u16* __restrict__ wt)
{
    int i = blockIdx.x * 256 + threadIdx.x;   // total 3*768*768
    int d = i % 768;
    int o = (i / 768) % 768;
    int m = i / (768 * 768);
    wt[i] = f2bf(w[((long)m * 768 + d) * 768 + o]);
}

// one block per row, 2048 bf16 logits in-place -> softmax probs (bf16)
__global__ __launch_bounds__(256) void softmax_kernel(u16* __restrict__ S)
{
    const long row = blockIdx.x;
    u16* p = S + row * 2048;
    const int t = threadIdx.x;
    const int lane = t & 63;
    const int wave = t >> 6;
    __shared__ float red[8];

    ushort8 raw = *(const ushort8*)(p + t * 8);
    float v[8];
    float m = -1e30f;
#pragma unroll
    for (int i = 0; i < 8; ++i) { v[i] = bf2f(raw[i]); m = fmaxf(m, v[i]); }
#pragma unroll
    for (int off = 1; off < 64; off <<= 1) m = fmaxf(m, __shfl_xor(m, off, 64));
    if (lane == 0) red[wave] = m;
    __syncthreads();
    m = fmaxf(fmaxf(red[0], red[1]), fmaxf(red[2], red[3]));

    float s = 0.f;
#pragma unroll
    for (int i = 0; i < 8; ++i) { v[i] = __expf(v[i] - m); s += v[i]; }
#pragma unroll
    for (int off = 1; off < 64; off <<= 1) s += __shfl_xor(s, off, 64);
    if (lane == 0) red[4 + wave] = s;
    __syncthreads();
    s = (red[4] + red[5]) + (red[6] + red[7]);

    const float inv = 1.0f / s;
    ushort8 out;
#pragma unroll
    for (int i = 0; i < 8; ++i) out[i] = f2bf(v[i] * inv);
    *(ushort8*)(p + t * 8) = out;
}

// ---------------------------------------------------------------------------
extern "C" void kernel_launch(void* const* d_in, const int* in_sizes, int n_in,
                              void* d_out, int out_size, void* d_ws, size_t ws_size,
                              hipStream_t stream)
{
    const float* x  = (const float*)d_in[0];   // [8,2048,768]
    const float* wk = (const float*)d_in[1];   // [3,768,768]
    float* out = (float*)d_out;                // [8,2048,768]

    char* ws = (char*)d_ws;
    u16* xbf = (u16*)(ws);                       // 16384x768        25.2 MB
    u16* wt  = (u16*)(ws + 25165824);            // 3x768x768 (W^T)   3.5 MB
    u16* qbf = (u16*)(ws + 28704768);            // 16384x768        25.2 MB
    u16* kbf = (u16*)(ws + 53870592);            // 16384x768        25.2 MB
    u16* vt  = (u16*)(ws + 79036416);            // 8x768x2048       25.2 MB
    u16* S   = (u16*)(ws + 104202240);           // 8x2048x2048      67.1 MB

    // 1. conversions
    cvt_x_kernel<<<dim3(12288), dim3(256), 0, stream>>>(
        (const float4*)x, (ushort4v*)xbf, 3145728);
    cvt_w_kernel<<<dim3(6912), dim3(256), 0, stream>>>(wk, wt);

    // 2. fused QKV projections (9 col-tiles of 256 share x row-tiles)
    gemm256<0><<<dim3(576), dim3(512), 0, stream>>>(
        xbf, wt, qbf, kbf, vt, 1.0f);

    // 3. logits: S_b = 0.125 * Q_b K_b^T   (batch <-> XCD)
    gemm256<1><<<dim3(512), dim3(512), 0, stream>>>(
        qbf, kbf, S, nullptr, nullptr, 0.125f);

    // 4. softmax rows (in place, bf16)
    softmax_kernel<<<dim3(16384), dim3(256), 0, stream>>>(S);

    // 5. out_b = A_b V_b
    gemm256<2><<<dim3(192), dim3(512), 0, stream>>>(
        S, vt, out, nullptr, nullptr, 1.0f);
}